// Round 1
// 305.971 us; speedup vs baseline: 1.0116x; 1.0116x over previous
//
#include <hip/hip_runtime.h>
#include <hip/hip_fp16.h>

typedef _Float16 half8   __attribute__((ext_vector_type(8)));
typedef _Float16 half4_t __attribute__((ext_vector_type(4)));
typedef float    f32x4   __attribute__((ext_vector_type(4)));

#define HDIM  1024
#define BATCH 32
#define TLEN  1024
#define M_TOT (BATCH * TLEN)

#define BM 128
#define BN 128
#define LDA 40   // fallback-path padded LDS stride (halves)

// ---------------- fused prep: We16 convert (blocks 0..1023), qproj (1024..2047), zero (2048..2175)
__global__ void prep_k(const float* __restrict__ W, const float* __restrict__ hidden,
                       const float* __restrict__ bias, _Float16* __restrict__ We16,
                       float* __restrict__ q, float* __restrict__ energ) {
    const int bid = blockIdx.x;
    const int t = threadIdx.x;
    if (bid < 1024) {
        int idx = bid * 256 + t;
        int g  = idx >> 8;
        int k4 = idx & 255;
        float4 f = *reinterpret_cast<const float4*>(W + (size_t)g * 2048 + 1024 + k4 * 4);
        half4_t h;
        h[0] = (_Float16)f.x; h[1] = (_Float16)f.y; h[2] = (_Float16)f.z; h[3] = (_Float16)f.w;
        *reinterpret_cast<half4_t*>(We16 + (size_t)idx * 4) = h;
    } else if (bid < 2048) {
        int g = bid - 1024;
        int wave = t >> 6, lane = t & 63;
        float acc[BATCH];
#pragma unroll
        for (int b = 0; b < BATCH; b++) acc[b] = 0.f;
        const float* wr = W + (size_t)g * 2048;
        for (int h = t; h < HDIM; h += 256) {
            float w = wr[h];
#pragma unroll
            for (int b = 0; b < BATCH; b++) acc[b] = fmaf(w, hidden[b * HDIM + h], acc[b]);
        }
        __shared__ float sm[4 * BATCH];
#pragma unroll
        for (int b = 0; b < BATCH; b++) {
            float s = acc[b];
#pragma unroll
            for (int off = 32; off >= 1; off >>= 1) s += __shfl_xor(s, off);
            if (lane == 0) sm[wave * BATCH + b] = s;
        }
        __syncthreads();
        if (t < BATCH) {
            float s = sm[t] + sm[BATCH + t] + sm[2 * BATCH + t] + sm[3 * BATCH + t];
            q[t * HDIM + g] = s + bias[g];
        }
    } else {
        energ[(bid - 2048) * 256 + t] = 0.f;
    }
}

// ---------------- convert enc (32M fp32) to fp16 ----------------
__global__ void enc_convert_k(const float* __restrict__ enc, _Float16* __restrict__ enc16) {
    size_t i = ((size_t)blockIdx.x * blockDim.x + threadIdx.x) * 8;
    float4 f0 = *reinterpret_cast<const float4*>(enc + i);
    float4 f1 = *reinterpret_cast<const float4*>(enc + i + 4);
    half8 h;
    h[0] = (_Float16)f0.x; h[1] = (_Float16)f0.y; h[2] = (_Float16)f0.z; h[3] = (_Float16)f0.w;
    h[4] = (_Float16)f1.x; h[5] = (_Float16)f1.y; h[6] = (_Float16)f1.z; h[7] = (_Float16)f1.w;
    *reinterpret_cast<half8*>(enc16 + i) = h;
}

__device__ __forceinline__ void async16(const void* g, void* l) {
    __builtin_amdgcn_global_load_lds(
        (const __attribute__((address_space(1))) void*)g,
        (__attribute__((address_space(3))) void*)l, 16, 0, 0);
}

// ---------------- FAST: 256x256 tile, BK=64, 8-wave, 8-phase counted-vmcnt schedule ------
// LDS: 2 buffers x (A 256x64 | B 256x64) fp16 = 128 KB. Half-tiles (128x64 = 16 KB) are the
// staging unit: 2 x global_load_lds(16B) per thread per phase. XOR chunk-swizzle applied via
// pre-swizzled GLOBAL source (linear LDS dest, required by global_load_lds) + swizzled read.
// Slot liveness (per K-tile, phases q1..q4): B-half last read q2, A-half last read q3.
// Stage order (steady state, one half-tile/phase):
//   p1: A0-buf1(t+1)  p2: A1-buf1(t+1)  p3: B0-buf0(t+2)  p4: B1-buf0(t+2)  [vmcnt(4)]
//   p5: A0-buf0(t+2)  p6: A1-buf0(t+2)  p7: B0-buf1(t+3)  p8: B1-buf1(t+3)  [vmcnt(4)]
// vmcnt(4) leaves the newest 2 half-tiles in flight and guarantees everything a subsequent
// phase reads has landed (verified by per-slot issue->read window analysis).
#define NIT 8    // iterations; 2 K-tiles each; K = 16*64 = 1024

__global__ __launch_bounds__(512, 2)
void attn_gemm8_k(const _Float16* __restrict__ enc16,
                  const _Float16* __restrict__ We16,
                  const float* __restrict__ q, const float* __restrict__ v,
                  float* __restrict__ energies) {
    __shared__ _Float16 lds[65536];   // [buf:2][A 16384 | B 16384] halves

    const int tid  = threadIdx.x;
    const int id   = blockIdx.x;
    // XCD-aware: 512 blocks round-robin over 8 XCDs; each XCD owns 16 m-stripes x 4 n-blocks
    const int xcd  = id & 7;
    const int w    = id >> 3;
    const int m0   = (xcd * 16 + (w >> 2)) * 256;
    const int n0   = (w & 3) * 256;

    const int wave = tid >> 6;
    const int lane = tid & 63;
    const int quad = lane >> 4;
    const int l16  = lane & 15;
    const int wm   = wave >> 2;       // 0/1: rows wm*128
    const int wn   = wave & 3;        // 0..3: cols wn*64
    const int hb   = wn >> 1;         // which B half-tile this wave reads

    // staging: thread tid covers (row = tid>>3 [+64], chunk c = tid&7); fetch global chunk c^(row&7)
    const int rA = tid >> 3;
    const int sc = ((tid & 7) ^ (rA & 7)) * 8;
    const _Float16* gA = enc16 + (size_t)(m0 + rA) * HDIM + sc;
    const _Float16* gB = We16  + (size_t)(n0 + rA) * HDIM + sc;

    // fragment read offsets (halves); swizzled chunk = (ks*4+quad) ^ (row&7), row&7 == l16&7
    const int cs0 = (quad ^ (l16 & 7)) * 8;
    const int cs1 = ((4 + quad) ^ (l16 & 7)) * 8;
    const int arow = wm * 8192 + l16 * 64;
    const int brow = 16384 + hb * 8192 + ((wn & 1) * 64 + l16) * 64;

    f32x4 acc[8][4];
#pragma unroll
    for (int i = 0; i < 8; i++)
#pragma unroll
        for (int j = 0; j < 4; j++) acc[i][j] = {0.f, 0.f, 0.f, 0.f};

    half8 aLo[4][2], aHi[4][2], bLo[2][2], bHi[2][2];

#define STAGE_A(buf, ha, kt) do { \
    _Float16* d_ = &lds[(buf)*32768 + (ha)*8192 + tid*8]; \
    const _Float16* s_ = gA + (size_t)(ha)*131072 + (kt)*64; \
    async16(s_, d_); async16(s_ + 65536, d_ + 4096); } while(0)

#define STAGE_B(buf, hbt, kt) do { \
    _Float16* d_ = &lds[(buf)*32768 + 16384 + (hbt)*8192 + tid*8]; \
    const _Float16* s_ = gB + (size_t)(hbt)*131072 + (kt)*64; \
    async16(s_, d_); async16(s_ + 65536, d_ + 4096); } while(0)

#define RD_ALO(bb) { _Pragma("unroll") for (int mi_ = 0; mi_ < 4; mi_++) { \
    aLo[mi_][0] = *reinterpret_cast<const half8*>(&lds[(bb)+arow+mi_*1024+cs0]); \
    aLo[mi_][1] = *reinterpret_cast<const half8*>(&lds[(bb)+arow+mi_*1024+cs1]); } }
#define RD_AHI(bb) { _Pragma("unroll") for (int mi_ = 0; mi_ < 4; mi_++) { \
    aHi[mi_][0] = *reinterpret_cast<const half8*>(&lds[(bb)+arow+(mi_+4)*1024+cs0]); \
    aHi[mi_][1] = *reinterpret_cast<const half8*>(&lds[(bb)+arow+(mi_+4)*1024+cs1]); } }
#define RD_BLO(bb) { _Pragma("unroll") for (int ni_ = 0; ni_ < 2; ni_++) { \
    bLo[ni_][0] = *reinterpret_cast<const half8*>(&lds[(bb)+brow+ni_*1024+cs0]); \
    bLo[ni_][1] = *reinterpret_cast<const half8*>(&lds[(bb)+brow+ni_*1024+cs1]); } }
#define RD_BHI(bb) { _Pragma("unroll") for (int ni_ = 0; ni_ < 2; ni_++) { \
    bHi[ni_][0] = *reinterpret_cast<const half8*>(&lds[(bb)+brow+(ni_+2)*1024+cs0]); \
    bHi[ni_][1] = *reinterpret_cast<const half8*>(&lds[(bb)+brow+(ni_+2)*1024+cs1]); } }

#define MFMA16(AF, BF, MO, NO) { _Pragma("unroll") for (int ks_ = 0; ks_ < 2; ks_++) \
    _Pragma("unroll") for (int mi_ = 0; mi_ < 4; mi_++) \
    _Pragma("unroll") for (int ni_ = 0; ni_ < 2; ni_++) \
      acc[mi_+MO][ni_+NO] = __builtin_amdgcn_mfma_f32_16x16x32_f16( \
          AF[mi_][ks_], BF[ni_][ks_], acc[mi_+MO][ni_+NO], 0, 0, 0); }

#define BAR1 { __builtin_amdgcn_s_barrier(); \
    asm volatile("s_waitcnt lgkmcnt(0)" ::: "memory"); \
    __builtin_amdgcn_sched_barrier(0); \
    __builtin_amdgcn_s_setprio(1); }
#define BAR2 { __builtin_amdgcn_s_setprio(0); \
    __builtin_amdgcn_s_barrier(); \
    __builtin_amdgcn_sched_barrier(0); }
#define BAR2V(n) { __builtin_amdgcn_s_setprio(0); \
    asm volatile("s_waitcnt vmcnt(" #n ")" ::: "memory"); \
    __builtin_amdgcn_s_barrier(); \
    __builtin_amdgcn_sched_barrier(0); }

    // prologue: tile 0 -> buf0 (all 4 half-tiles); tile 1 B -> buf1. 12 loads; drain 8.
    STAGE_A(0, 0, 0); STAGE_A(0, 1, 0); STAGE_B(0, 0, 0); STAGE_B(0, 1, 0);
    STAGE_B(1, 0, 1); STAGE_B(1, 1, 1);
    asm volatile("s_waitcnt vmcnt(4)" ::: "memory");
    __builtin_amdgcn_s_barrier();
    __builtin_amdgcn_sched_barrier(0);

    for (int i = 0; i < NIT; i++) {
        const int kt1 = 2 * i + 1, kt2 = 2 * i + 2, kt3 = 2 * i + 3;
        const bool more = (i < NIT - 1);
        // ---- K-tile 2i from buf0 ----
        RD_ALO(0); RD_BLO(0);            STAGE_A(1, 0, kt1);
        BAR1; MFMA16(aLo, bLo, 0, 0); BAR2;
        RD_BHI(0);                       STAGE_A(1, 1, kt1);
        BAR1; MFMA16(aLo, bHi, 0, 2); BAR2;
        RD_AHI(0);                       if (more) STAGE_B(0, 0, kt2);
        BAR1; MFMA16(aHi, bHi, 4, 2); BAR2;
                                         if (more) STAGE_B(0, 1, kt2);
        BAR1; MFMA16(aHi, bLo, 4, 0);
        if (more) { BAR2V(4); } else { BAR2V(0); }
        // ---- K-tile 2i+1 from buf1 ----
        RD_ALO(32768); RD_BLO(32768);    if (more) STAGE_A(0, 0, kt2);
        BAR1; MFMA16(aLo, bLo, 0, 0); BAR2;
        RD_BHI(32768);                   if (more) STAGE_A(0, 1, kt2);
        BAR1; MFMA16(aLo, bHi, 0, 2); BAR2;
        RD_AHI(32768);                   if (more) STAGE_B(1, 0, kt3);
        BAR1; MFMA16(aHi, bHi, 4, 2); BAR2;
                                         if (more) STAGE_B(1, 1, kt3);
        BAR1; MFMA16(aHi, bLo, 4, 0);
        if (more) { BAR2V(4); } else { BAR2; }
    }

    // epilogue: C/D frag layout col = l16, row = quad*4 + r (verified in prior kernel)
    const int bidx = m0 >> 10;
    const int gb = n0 + wn * 64;
    float qv[4], vv[4];
#pragma unroll
    for (int ni = 0; ni < 4; ni++) {
        int g = gb + ni * 16 + l16;
        qv[ni] = q[bidx * HDIM + g];
        vv[ni] = v[g];
    }
#pragma unroll
    for (int mi = 0; mi < 8; mi++) {
#pragma unroll
        for (int r = 0; r < 4; r++) {
            int row = m0 + wm * 128 + mi * 16 + quad * 4 + r;
            float s = 0.f;
#pragma unroll
            for (int ni = 0; ni < 4; ni++) {
                float pre = acc[mi][ni][r] + qv[ni];
                float e = __expf(2.f * pre);
                float th = 1.f - 2.f / (e + 1.f);
                s = fmaf(th, vv[ni], s);
            }
            s += __shfl_xor(s, 1);
            s += __shfl_xor(s, 2);
            s += __shfl_xor(s, 4);
            s += __shfl_xor(s, 8);
            if (l16 == 0) atomicAdd(&energies[row], s);
        }
    }
#undef STAGE_A
#undef STAGE_B
#undef RD_ALO
#undef RD_AHI
#undef RD_BLO
#undef RD_BHI
#undef MFMA16
#undef BAR1
#undef BAR2
#undef BAR2V
}

// ---------------- FALLBACK: fp32 A on-the-fly convert (BK=32, padded LDS) ----------------
__global__ __launch_bounds__(256, 2)
void attn_gemm_k(const float* __restrict__ enc, const _Float16* __restrict__ We16,
                 const float* __restrict__ q, const float* __restrict__ v,
                 float* __restrict__ energies) {
    __shared__ _Float16 As[BM * LDA];
    __shared__ _Float16 Bs[BN * LDA];

    const int tid  = threadIdx.x;
    const int m0   = blockIdx.x * BM;
    const int n0   = blockIdx.y * BN;
    const int wave = tid >> 6;
    const int lane = tid & 63;
    const int quad = lane >> 4;
    const int l16  = lane & 15;
    const int wm   = (wave & 1) * 64;
    const int wn   = (wave >> 1) * 64;

    const int srow = tid >> 1;
    const int scol = (tid & 1) * 16;

    f32x4 acc[4][4];
#pragma unroll
    for (int i = 0; i < 4; i++)
#pragma unroll
        for (int j = 0; j < 4; j++) acc[i][j] = {0.f, 0.f, 0.f, 0.f};

    const float*    ag = enc  + (size_t)(m0 + srow) * HDIM + scol;
    const _Float16* bg = We16 + (size_t)(n0 + srow) * HDIM + scol;
    _Float16* aw = &As[srow * LDA + scol];
    _Float16* bw = &Bs[srow * LDA + scol];

    for (int k0 = 0; k0 < HDIM; k0 += 32) {
        float4 a0 = *reinterpret_cast<const float4*>(ag + k0 + 0);
        float4 a1 = *reinterpret_cast<const float4*>(ag + k0 + 4);
        float4 a2 = *reinterpret_cast<const float4*>(ag + k0 + 8);
        float4 a3 = *reinterpret_cast<const float4*>(ag + k0 + 12);
        float4 b0 = *reinterpret_cast<const float4*>(bg + k0);
        float4 b1 = *reinterpret_cast<const float4*>(bg + k0 + 8);

        __syncthreads();

        half8 ha0, ha1;
        ha0[0] = (_Float16)a0.x; ha0[1] = (_Float16)a0.y; ha0[2] = (_Float16)a0.z; ha0[3] = (_Float16)a0.w;
        ha0[4] = (_Float16)a1.x; ha0[5] = (_Float16)a1.y; ha0[6] = (_Float16)a1.z; ha0[7] = (_Float16)a1.w;
        ha1[0] = (_Float16)a2.x; ha1[1] = (_Float16)a2.y; ha1[2] = (_Float16)a2.z; ha1[3] = (_Float16)a2.w;
        ha1[4] = (_Float16)a3.x; ha1[5] = (_Float16)a3.y; ha1[6] = (_Float16)a3.z; ha1[7] = (_Float16)a3.w;
        *reinterpret_cast<half8*>(aw)     = ha0;
        *reinterpret_cast<half8*>(aw + 8) = ha1;
        *reinterpret_cast<float4*>(bw)     = b0;
        *reinterpret_cast<float4*>(bw + 8) = b1;

        __syncthreads();

        half8 af[4], bf[4];
#pragma unroll
        for (int i = 0; i < 4; i++) {
            af[i] = *reinterpret_cast<const half8*>(&As[(wm + i * 16 + l16) * LDA + quad * 8]);
            bf[i] = *reinterpret_cast<const half8*>(&Bs[(wn + i * 16 + l16) * LDA + quad * 8]);
        }
#pragma unroll
        for (int mi = 0; mi < 4; mi++)
#pragma unroll
            for (int ni = 0; ni < 4; ni++)
                acc[mi][ni] = __builtin_amdgcn_mfma_f32_16x16x32_f16(af[mi], bf[ni], acc[mi][ni], 0, 0, 0);
    }

    const int bidx = m0 >> 10;
    float qv[4], vv[4];
#pragma unroll
    for (int ni = 0; ni < 4; ni++) {
        int g = n0 + wn + ni * 16 + l16;
        qv[ni] = q[bidx * HDIM + g];
        vv[ni] = v[g];
    }
#pragma unroll
    for (int mi = 0; mi < 4; mi++) {
#pragma unroll
        for (int r = 0; r < 4; r++) {
            int row = wm + mi * 16 + quad * 4 + r;
            float s = 0.f;
#pragma unroll
            for (int ni = 0; ni < 4; ni++) {
                float pre = acc[mi][ni][r] + qv[ni];
                float e = __expf(2.f * pre);
                float th = 1.f - 2.f / (e + 1.f);
                s = fmaf(th, vv[ni], s);
            }
            s += __shfl_xor(s, 1);
            s += __shfl_xor(s, 2);
            s += __shfl_xor(s, 4);
            s += __shfl_xor(s, 8);
            if (l16 == 0) atomicAdd(&energies[m0 + row], s);
        }
    }
}

// ---------------- softmax over t per batch row ----------------
__global__ void softmax_k(const float* __restrict__ energies, float* __restrict__ out) {
    int b = blockIdx.x;
    int t = threadIdx.x;
    int wave = t >> 6, lane = t & 63;
    __shared__ float smax[4], ssum[4];
    float e[4];
#pragma unroll
    for (int i = 0; i < 4; i++) e[i] = energies[b * TLEN + t + i * 256];
    float m = fmaxf(fmaxf(e[0], e[1]), fmaxf(e[2], e[3]));
#pragma unroll
    for (int off = 32; off >= 1; off >>= 1) m = fmaxf(m, __shfl_xor(m, off));
    if (lane == 0) smax[wave] = m;
    __syncthreads();
    float M = fmaxf(fmaxf(smax[0], smax[1]), fmaxf(smax[2], smax[3]));
    float x[4]; float s = 0.f;
#pragma unroll
    for (int i = 0; i < 4; i++) { x[i] = __expf(e[i] - M); s += x[i]; }
#pragma unroll
    for (int off = 32; off >= 1; off >>= 1) s += __shfl_xor(s, off);
    if (lane == 0) ssum[wave] = s;
    __syncthreads();
    float S = ssum[0] + ssum[1] + ssum[2] + ssum[3];
    float inv = 1.f / S;
#pragma unroll
    for (int i = 0; i < 4; i++) out[b * TLEN + t + i * 256] = x[i] * inv;
}

extern "C" void kernel_launch(void* const* d_in, const int* in_sizes, int n_in,
                              void* d_out, int out_size, void* d_ws, size_t ws_size,
                              hipStream_t stream) {
    const float* hidden = (const float*)d_in[0];   // (1, 32, 1024) fp32
    const float* enc    = (const float*)d_in[1];   // (32, 1024, 1024) fp32
    const float* W      = (const float*)d_in[2];   // (1024, 2048) fp32
    const float* bias   = (const float*)d_in[3];   // (1024,) fp32
    const float* v      = (const float*)d_in[4];   // (1024,) fp32
    float* out = (float*)d_out;                    // (32, 1, 1024) fp32

    char* ws = (char*)d_ws;
    float*    q     = (float*)ws;                  // 128 KB
    float*    energ = (float*)(ws + 131072);       // 128 KB
    _Float16* We16  = (_Float16*)(ws + 262144);    // 2 MB
    _Float16* enc16 = (_Float16*)(ws + 262144 + 2097152);  // 64 MB
    const size_t need_fast = 262144 + 2097152 + (size_t)M_TOT * HDIM * 2;  // ~66.3 MB

    // prep: blocks 0..1023 we_convert, 1024..2047 qproj, 2048..2175 zero energies
    prep_k<<<dim3(2176), 256, 0, stream>>>(W, hidden, bias, We16, q, energ);
    if (ws_size >= need_fast) {
        enc_convert_k<<<dim3((size_t)M_TOT * HDIM / 8 / 256), 256, 0, stream>>>(enc, enc16);
        attn_gemm8_k<<<dim3(512), 512, 0, stream>>>(enc16, We16, q, v, energ);
    } else {
        attn_gemm_k<<<dim3(256, 8), 256, 0, stream>>>(enc, We16, q, v, energ);
    }
    softmax_k<<<dim3(BATCH), 256, 0, stream>>>(energ, out);
}